// Round 8
// baseline (9070.031 us; speedup 1.0000x reference)
//
#include <hip/hip_runtime.h>
#include <hip/hip_bf16.h>
#include <hip/hip_cooperative_groups.h>

namespace cg = cooperative_groups;

typedef unsigned short ushort_t;
typedef unsigned int uint32;
typedef __attribute__((ext_vector_type(8))) __bf16 bf16x8;
typedef __attribute__((ext_vector_type(4))) float f32x4;
typedef __attribute__((ext_vector_type(4))) unsigned int u32x4;

#define SEQ_LEN 1024
#define NWG 64
#define NTHR 256

#define WPACK_BYTES (4ull << 20)                   /* 64 WG * 64KB frag-major W  */
#define HB_OFF  WPACK_BYTES                        /* rotating h: 1024 slots x 64KB = 64MB */
#define FLG_OFF (HB_OFF + (64ull << 20))           /* 256 per-wave flags, 1KB (zeroed 4KB) */
#define WS_NEED (FLG_OFF + (4ull << 10))

__device__ __forceinline__ ushort_t f2bf(float f) {
  unsigned u = __builtin_bit_cast(unsigned, f);
  unsigned r = (u + 0x7fffu + ((u >> 16) & 1u)) >> 16;
  return (ushort_t)r;
}
__device__ __forceinline__ float sigm(float x) {
  float e = __expf(-x);
  return __builtin_amdgcn_rcpf(1.f + e);
}
__device__ __forceinline__ float tanh_fast(float x) {
  float a = fabsf(x);
  float e = __expf(-2.f * a);
  float r = (1.f - e) * __builtin_amdgcn_rcpf(1.f + e);
  return copysignf(r, x);
}

__global__ void zero_mem_kernel(u32x4* p) {
  int i = blockIdx.x * blockDim.x + threadIdx.x;
  u32x4 z = {0u, 0u, 0u, 0u};
  p[i] = z;
}

// pack W = [W_i; W_h] per-WG frag-major: col = gate*512 + wg*8 + tau*4 + hcl,
// lane = 16*hi + (hcl<<2|gate), k = 32kk+8hi+r, dst [wg][kk(0..31)][tau][lane][r]
__global__ void pack_w_kernel(const float* __restrict__ Wi, const float* __restrict__ Wh,
                              ushort_t* __restrict__ wp) {
  unsigned e = blockIdx.x * blockDim.x + threadIdx.x;  // 1024*2048
  int k = e >> 11;
  int col = e & 2047;
  float v = (k < 512) ? Wi[(size_t)k * 2048 + col] : Wh[(size_t)(k - 512) * 2048 + col];
  int wg  = (col & 511) >> 3;
  int tau = (col >> 2) & 1;
  int hcl = col & 3;
  int gate = col >> 9;
  int p = (hcl << 2) | gate;
  int kk = k >> 5;
  int hi = (k >> 3) & 3;
  int r = k & 7;
  int lane = (hi << 4) | p;
  wp[(size_t)wg * 32768 + (size_t)(((kk * 2) + tau) * 64 + lane) * 8 + r] = f2bf(v);
}

// persistent LSTM. Per WG: 8 h-cols (2 MFMA tiles of 16 gate-cols each).
// D layout: col = lane&15 (batch), row = 4*(lane>>4)+reg = (hcl<<2|gate)
// => each lane owns h-cols kh0 = wg*8+(lane>>4), kh1 = kh0+4, gates = regs.
// FAST: weights fully VGPR-resident (no LDS). h exchanged via WRITE-ONCE
// rotating slots (64KB per t): consumers read with PLAIN CACHED loads
// (any cached copy is provably fresh: nobody touches slot t pre-flag),
// so the 8 WGs/XCD share one L2 fill. Producers: sc1 stores -> vmcnt drain
// -> per-wave sc1 flag (monotone). Consumer waits only on same-wave-index
// producer flags (64 dwords). Plain launch. Slow path: cooperative grid.sync.
template<bool FAST>
__global__ void __launch_bounds__(NTHR, 1)
lstm_coop(const float* __restrict__ x, const float* __restrict__ Wi,
          const float* __restrict__ Wh, const float* __restrict__ bias,
          const u32x4* __restrict__ wpack, ushort_t* hbuf16, uint32* flags, float* out)
{
  __shared__ u32x4 lA[FAST ? 1 : 4096];
  const int tid  = threadIdx.x;
  const int wg   = blockIdx.x;
  const int lane = tid & 63;
  const int wv   = tid >> 6;
  const int hi2  = lane >> 4;
  const int lo   = lane & 15;
  const int b    = (wv << 4) | lo;

  // weight fragments: x-part (wxA/wxB) and h-part (whA/whB), 64 frags = 256 VGPR
  bf16x8 wxA[16], wxB[16], whA[16], whB[16];

  if constexpr (FAST) {
    const u32x4* wsrc = wpack + (size_t)wg * 4096;
#pragma unroll
    for (int kk = 0; kk < 16; ++kk) {
      wxA[kk] = __builtin_bit_cast(bf16x8, wsrc[(kk * 2 + 0) * 64 + lane]);
      wxB[kk] = __builtin_bit_cast(bf16x8, wsrc[(kk * 2 + 1) * 64 + lane]);
      whA[kk] = __builtin_bit_cast(bf16x8, wsrc[((16 + kk) * 2 + 0) * 64 + lane]);
      whB[kk] = __builtin_bit_cast(bf16x8, wsrc[((16 + kk) * 2 + 1) * 64 + lane]);
    }
  } else {
    for (int uu = tid; uu < 4096; uu += NTHR) {
      int ln = uu & 63, tau = (uu >> 6) & 1, kk = uu >> 7;
      int uhi = ln >> 4, p = ln & 15;
      int gate = p & 3, hcl = p >> 2;
      int col = gate * 512 + (wg << 3) + tau * 4 + hcl;
      ushort_t tmp[8];
#pragma unroll
      for (int r = 0; r < 8; ++r) {
        int k = (kk << 5) + (uhi << 3) + r;
        float f = (k < 512) ? Wi[(size_t)k * 2048 + col] : Wh[(size_t)(k - 512) * 2048 + col];
        tmp[r] = f2bf(f);
      }
      u32x4 v;
      v[0] = tmp[0] | ((uint32)tmp[1] << 16);
      v[1] = tmp[2] | ((uint32)tmp[3] << 16);
      v[2] = tmp[4] | ((uint32)tmp[5] << 16);
      v[3] = tmp[6] | ((uint32)tmp[7] << 16);
      lA[uu] = v;
    }
    __syncthreads();
#pragma unroll
    for (int kk = 0; kk < 16; ++kk) {
      whA[kk] = __builtin_bit_cast(bf16x8, lA[((16 + kk) * 2 + 0) * 64 + lane]);
      whB[kk] = __builtin_bit_cast(bf16x8, lA[((16 + kk) * 2 + 1) * 64 + lane]);
    }
  }

  const int kh0 = (wg << 3) | hi2;
  const int kh1 = kh0 + 4;
  const float b00 = bias[0 * 512 + kh0], b01 = bias[1 * 512 + kh0];
  const float b02 = bias[2 * 512 + kh0], b03 = bias[3 * 512 + kh0];
  const float b10 = bias[0 * 512 + kh1], b11 = bias[1 * 512 + kh1];
  const float b12 = bias[2 * 512 + kh1], b13 = bias[3 * 512 + kh1];

  // element offset (u16 units) within one 64KB slot
  const int hoff0 = (((kh0 >> 5) * 256 + b * 4 + ((kh0 >> 3) & 3)) << 3) + (kh0 & 7);
  const int hoff1 = hoff0 + 4;

  float c0 = 0.f, c1 = 0.f, hn0 = 0.f, hn1 = 0.f;

  for (int t = 0; t < SEQ_LEN; ++t) {
    // ---- x-projection (independent of h; hides producer store propagation) ----
    f32x4 ax0 = {b00, b01, b02, b03};
    f32x4 ax1 = {b10, b11, b12, b13};
    {
      const float* xr = x + ((size_t)b * SEQ_LEN + t) * 512 + (hi2 << 3);
#pragma unroll
      for (int kk = 0; kk < 16; ++kk) {
        f32x4 f0 = *(const f32x4*)(xr + (kk << 5));
        f32x4 f1 = *(const f32x4*)(xr + (kk << 5) + 4);
        u32x4 v;
        v[0] = f2bf(f0[0]) | ((uint32)f2bf(f0[1]) << 16);
        v[1] = f2bf(f0[2]) | ((uint32)f2bf(f0[3]) << 16);
        v[2] = f2bf(f1[0]) | ((uint32)f2bf(f1[1]) << 16);
        v[3] = f2bf(f1[2]) | ((uint32)f2bf(f1[3]) << 16);
        bf16x8 xv = __builtin_bit_cast(bf16x8, v);
        if constexpr (FAST) {
          ax0 = __builtin_amdgcn_mfma_f32_16x16x32_bf16(wxA[kk], xv, ax0, 0, 0, 0);
          ax1 = __builtin_amdgcn_mfma_f32_16x16x32_bf16(wxB[kk], xv, ax1, 0, 0, 0);
        } else {
          bf16x8 a0 = __builtin_bit_cast(bf16x8, lA[(kk * 2 + 0) * 64 + lane]);
          bf16x8 a1 = __builtin_bit_cast(bf16x8, lA[(kk * 2 + 1) * 64 + lane]);
          ax0 = __builtin_amdgcn_mfma_f32_16x16x32_bf16(a0, xv, ax0, 0, 0, 0);
          ax1 = __builtin_amdgcn_mfma_f32_16x16x32_bf16(a1, xv, ax1, 0, 0, 0);
        }
      }
    }

    f32x4 ah0 = {0.f, 0.f, 0.f, 0.f};
    f32x4 ah1 = {0.f, 0.f, 0.f, 0.f};

    if constexpr (FAST) {
      // ---- wait for h_t: only same-wave-index producers matter (64 flags) ----
      if (t > 0) {
        const uint32* fa = flags + (lane << 2) + wv;   // lane L -> WG L, wave wv
        const uint32 tt = (uint32)t;
        while (true) {
          uint32 v;
          asm volatile("global_load_dword %0, %1, off sc0 sc1\n\ts_waitcnt vmcnt(0)"
                       : "=v"(v) : "v"(fa) : "memory");
          if (__all(v >= tt)) break;
        }
        __builtin_amdgcn_sched_barrier(0);
      }
      // ---- plain cached h load from write-once slot t (L2-shared per XCD) ----
      const u32x4* hr = (const u32x4*)(hbuf16 + (size_t)t * 32768) + b * 4 + hi2;
      u32x4 hreg[16];
#pragma unroll
      for (int kk = 0; kk < 16; ++kk) hreg[kk] = hr[kk * 256];
#pragma unroll
      for (int kk = 0; kk < 16; ++kk) {
        bf16x8 hv = __builtin_bit_cast(bf16x8, hreg[kk]);
        ah0 = __builtin_amdgcn_mfma_f32_16x16x32_bf16(whA[kk], hv, ah0, 0, 0, 0);
        ah1 = __builtin_amdgcn_mfma_f32_16x16x32_bf16(whB[kk], hv, ah1, 0, 0, 0);
      }
    } else {
      const u32x4* hr = (const u32x4*)hbuf16 + (size_t)(t & 1) * 4096 + b * 4 + hi2;
#pragma unroll
      for (int kk = 0; kk < 16; ++kk) {
        bf16x8 hv = __builtin_bit_cast(bf16x8, hr[kk * 256]);
        ah0 = __builtin_amdgcn_mfma_f32_16x16x32_bf16(whA[kk], hv, ah0, 0, 0, 0);
        ah1 = __builtin_amdgcn_mfma_f32_16x16x32_bf16(whB[kk], hv, ah1, 0, 0, 0);
      }
    }

    // ---- cell update (2 cells per lane) ----
    {
      float gi = ax0[0] + ah0[0], gf = ax0[1] + ah0[1];
      float gg = ax0[2] + ah0[2], go = ax0[3] + ah0[3];
      float it = sigm(gi), ft = sigm(gf), ot = sigm(go), gt = tanh_fast(gg);
      c0 = ft * c0 + it * gt;
      hn0 = ot * tanh_fast(c0);
    }
    {
      float gi = ax1[0] + ah1[0], gf = ax1[1] + ah1[1];
      float gg = ax1[2] + ah1[2], go = ax1[3] + ah1[3];
      float it = sigm(gi), ft = sigm(gf), ot = sigm(go), gt = tanh_fast(gg);
      c1 = ft * c1 + it * gt;
      hn1 = ot * tanh_fast(c1);
    }

    if (t < SEQ_LEN - 1) {
      if constexpr (FAST) {
        ushort_t* hw = hbuf16 + (size_t)(t + 1) * 32768;   // write-once slot t+1
        uint32 v0 = f2bf(hn0), v1 = f2bf(hn1);
        asm volatile("global_store_short %0, %1, off sc0 sc1"
                     :: "v"(hw + hoff0), "v"(v0) : "memory");
        asm volatile("global_store_short %0, %1, off sc0 sc1"
                     :: "v"(hw + hoff1), "v"(v1) : "memory");
        asm volatile("s_waitcnt vmcnt(0)" ::: "memory");
        __builtin_amdgcn_sched_barrier(0);
        if (lane == 0) {                       // per-wave monotone flag
          uint32* fp = flags + (wg << 2) + wv;
          uint32 val = (uint32)(t + 1);
          asm volatile("global_store_dword %0, %1, off sc0 sc1"
                       :: "v"(fp), "v"(val) : "memory");
        }
      } else {
        ushort_t* hw = hbuf16 + (size_t)((t + 1) & 1) * 32768;
        hw[hoff0] = f2bf(hn0);
        hw[hoff1] = f2bf(hn1);
        __threadfence();
        cg::this_grid().sync();
        __threadfence();
      }
    } else {
      if constexpr (!FAST) {
        __threadfence();
        cg::this_grid().sync();   // d_out aliases hbuf in slow path
      }
    }
  }

  out[(size_t)b * 512 + kh0] = hn0;
  out[(size_t)b * 512 + kh1] = hn1;
  out[32768 + (size_t)b * 512 + kh0] = c0;
  out[32768 + (size_t)b * 512 + kh1] = c1;
}

extern "C" void kernel_launch(void* const* d_in, const int* in_sizes, int n_in,
                              void* d_out, int out_size, void* d_ws, size_t ws_size,
                              hipStream_t stream) {
  const float* x    = (const float*)d_in[0];
  const float* Wi   = (const float*)d_in[1];
  const float* Wh   = (const float*)d_in[2];
  const float* bias = (const float*)d_in[3];
  float* out = (float*)d_out;

  bool fast = (d_ws != nullptr) && (ws_size >= WS_NEED);

  if (fast) {
    const u32x4* wpack = (const u32x4*)d_ws;
    ushort_t* hbuf16 = (ushort_t*)((char*)d_ws + HB_OFF);
    uint32* flags    = (uint32*)((char*)d_ws + FLG_OFF);

    // zero slot 0 (64KB) and flags (4KB); slots 1..1023 are write-once
    zero_mem_kernel<<<16, 256, 0, stream>>>((u32x4*)((char*)d_ws + HB_OFF));
    zero_mem_kernel<<<1, 256, 0, stream>>>((u32x4*)((char*)d_ws + FLG_OFF));
    pack_w_kernel<<<8192, 256, 0, stream>>>(Wi, Wh, (ushort_t*)d_ws);

    lstm_coop<true><<<dim3(NWG), dim3(NTHR), 0, stream>>>(
        x, Wi, Wh, bias, wpack, hbuf16, flags, out);
  } else {
    ushort_t* hbuf16 = (ushort_t*)d_out;  // h double-buffer inside d_out
    uint32* flags = (uint32*)d_out;       // unused on slow path
    const u32x4* wpack = (const u32x4*)Wi;

    zero_mem_kernel<<<16, 256, 0, stream>>>((u32x4*)d_out);  // 64KB slot0

    void* args[] = {(void*)&x, (void*)&Wi, (void*)&Wh, (void*)&bias,
                    (void*)&wpack, (void*)&hbuf16, (void*)&flags, (void*)&out};
    void (*kfn)(const float*, const float*, const float*, const float*,
                const u32x4*, ushort_t*, uint32*, float*) = lstm_coop<false>;
    hipLaunchCooperativeKernel(reinterpret_cast<void*>(kfn), dim3(NWG), dim3(NTHR),
                               args, 0, stream);
  }
}

// Round 9
// 3883.234 us; speedup vs baseline: 2.3357x; 2.3357x over previous
//
#include <hip/hip_runtime.h>
#include <hip/hip_bf16.h>
#include <hip/hip_cooperative_groups.h>

namespace cg = cooperative_groups;

typedef unsigned short ushort_t;
typedef unsigned int uint32;
typedef __attribute__((ext_vector_type(8))) __bf16 bf16x8;
typedef __attribute__((ext_vector_type(4))) float f32x4;
typedef __attribute__((ext_vector_type(4))) unsigned int u32x4;

#define SEQ_LEN 1024
#define NWG 32
#define NTHR 256

#define XPACK_BYTES (64ull << 20)                /* dense per-wave x frags */
#define WPACK_BYTES (4ull << 20)                 /* 32 WG * 128KB frag-major W */
#define HB_OFF  (XPACK_BYTES + WPACK_BYTES)      /* h double buffer, 2 x 64KB */
#define FLG_OFF (HB_OFF + (128ull << 10))        /* 128 flags (512B), 4KB region */
#define WS_NEED (FLG_OFF + (4ull << 10))

__device__ __forceinline__ ushort_t f2bf(float f) {
  unsigned u = __builtin_bit_cast(unsigned, f);
  unsigned r = (u + 0x7fffu + ((u >> 16) & 1u)) >> 16;
  return (ushort_t)r;
}
__device__ __forceinline__ float sigm(float x) {
  float e = __expf(-x);
  return __builtin_amdgcn_rcpf(1.f + e);
}
__device__ __forceinline__ float tanh_fast(float x) {
  float a = fabsf(x);
  float e = __expf(-2.f * a);
  float r = (1.f - e) * __builtin_amdgcn_rcpf(1.f + e);
  return copysignf(r, x);
}

__global__ void zero_mem_kernel(u32x4* p) {
  int i = blockIdx.x * blockDim.x + threadIdx.x;
  u32x4 z = {0u, 0u, 0u, 0u};
  p[i] = z;
}

// pack x f32 -> bf16 into DENSE per-wave frag layout:
// unit(t, bq, kk, lane) ; lane = hi2*16+lo ; b = bq*16+lo ; k = kk*32+hi2*8+r.
// Consumer wave wv reads units [t*4096 + wv*1024 + kk*64 + lane] -> 1KB dense/instr.
__global__ void pack_x_kernel(const float* __restrict__ x, u32x4* __restrict__ xp) {
  unsigned u = blockIdx.x * blockDim.x + threadIdx.x;   // 4M units
  int lane = u & 63;
  int kk   = (u >> 6) & 15;
  int bq   = (u >> 10) & 3;
  int t    = u >> 12;
  int hi2 = lane >> 4, lo = lane & 15;
  int b  = bq * 16 + lo;
  int k0 = kk * 32 + hi2 * 8;
  const float* src = x + ((size_t)b * SEQ_LEN + t) * 512 + k0;
  f32x4 f0 = *(const f32x4*)(src);
  f32x4 f1 = *(const f32x4*)(src + 4);
  u32x4 o;
  o[0] = f2bf(f0[0]) | ((uint32)f2bf(f0[1]) << 16);
  o[1] = f2bf(f0[2]) | ((uint32)f2bf(f0[3]) << 16);
  o[2] = f2bf(f1[0]) | ((uint32)f2bf(f1[1]) << 16);
  o[3] = f2bf(f1[2]) | ((uint32)f2bf(f1[3]) << 16);
  xp[u] = o;
}

// pack W = [W_i; W_h] per-WG frag-major (NWG=32, 4 tiles/WG):
// col = gate*512 + wg*16 + tau*4 + hcl ; lane = hi*16 + (hcl<<2|gate) ;
// k = 32kk+8hi+r ; dst ushort idx = wg*65536 + ((kk*4+tau)*64+lane)*8 + r.
__global__ void pack_w_kernel(const float* __restrict__ Wi, const float* __restrict__ Wh,
                              ushort_t* __restrict__ wp) {
  unsigned e = blockIdx.x * blockDim.x + threadIdx.x;  // 1024*2048
  int k = e >> 11;
  int col = e & 2047;
  float v = (k < 512) ? Wi[(size_t)k * 2048 + col] : Wh[(size_t)(k - 512) * 2048 + col];
  int wg  = (col & 511) >> 4;
  int tau = (col >> 2) & 3;
  int hcl = col & 3;
  int gate = col >> 9;
  int p = (hcl << 2) | gate;
  int kk = k >> 5;
  int hi = (k >> 3) & 3;
  int r = k & 7;
  int lane = (hi << 4) | p;
  wp[(size_t)wg * 65536 + (size_t)((kk * 4 + tau) * 64 + lane) * 8 + r] = f2bf(v);
}

// persistent LSTM, NWG=32. Per WG: 16 h-cols (4 tiles tau=0..3), 128KB LDS W.
// D layout: col = lane&15 (batch), row = 4*(lane>>4)+reg = (hcl<<2|gate)
// => lane owns h-cols kh(tau) = wg*16+tau*4+hi2, gates in regs. 4 cells/lane.
// h exchange: DENSE layout, unit = bq*1024 + (k>>5)*64 + ((k>>3)&3)*16 + lo
// (byte = unit*16 + (k&7)*2) -> consumer wave reads 16KB contiguous, 1KB/instr.
// Sync (R3-proven): producer sc stores -> vmcnt(0) -> per-wave sc flag;
// consumer polls the 32 same-wave-index flags (one dense 128B load), then
// sc bulk-loads h. FAST = plain launch; slow = cooperative grid.sync.
template<bool FAST>
__global__ void __launch_bounds__(NTHR, 1)
lstm_coop(const float* __restrict__ x, const float* __restrict__ Wi,
          const float* __restrict__ Wh, const float* __restrict__ bias,
          const u32x4* __restrict__ xpack, const u32x4* __restrict__ wpack,
          ushort_t* hbuf, uint32* flags, float* out)
{
  __shared__ u32x4 lA[8192];   // 128KB: [kk 0..31][tau 0..3][lane 0..63]
  const int tid  = threadIdx.x;
  const int wg   = blockIdx.x;
  const int lane = tid & 63;
  const int wv   = tid >> 6;
  const int hi2  = lane >> 4;
  const int lo   = lane & 15;
  const int b    = (wv << 4) | lo;

  if constexpr (FAST) {
    const u32x4* wsrc = wpack + (size_t)wg * 8192;
    for (int i = tid; i < 8192; i += NTHR) lA[i] = wsrc[i];
  } else {
    for (int uu = tid; uu < 8192; uu += NTHR) {
      int ln = uu & 63, tau = (uu >> 6) & 3, kk = uu >> 8;
      int uhi = ln >> 4, p = ln & 15;
      int gate = p & 3, hcl = p >> 2;
      int col = gate * 512 + (wg << 4) + tau * 4 + hcl;
      ushort_t tmp[8];
#pragma unroll
      for (int r = 0; r < 8; ++r) {
        int k = (kk << 5) + (uhi << 3) + r;
        float f = (k < 512) ? Wi[(size_t)k * 2048 + col] : Wh[(size_t)(k - 512) * 2048 + col];
        tmp[r] = f2bf(f);
      }
      u32x4 v;
      v[0] = tmp[0] | ((uint32)tmp[1] << 16);
      v[1] = tmp[2] | ((uint32)tmp[3] << 16);
      v[2] = tmp[4] | ((uint32)tmp[5] << 16);
      v[3] = tmp[6] | ((uint32)tmp[7] << 16);
      lA[uu] = v;
    }
  }
  __syncthreads();

  int kh[4], uoff[4];
  float bia[4][4];
#pragma unroll
  for (int tau = 0; tau < 4; ++tau) {
    int k = (wg << 4) + tau * 4 + hi2;
    kh[tau] = k;
    uoff[tau] = ((wv * 1024 + (k >> 5) * 64 + ((k >> 3) & 3) * 16 + lo) << 3) + (k & 7);
#pragma unroll
    for (int g = 0; g < 4; ++g) bia[tau][g] = bias[g * 512 + k];
  }

  float c[4] = {0.f, 0.f, 0.f, 0.f};
  float hn[4] = {0.f, 0.f, 0.f, 0.f};

  for (int t = 0; t < SEQ_LEN; ++t) {
    // ---- x-projection (independent of h; hides producer store propagation) ----
    f32x4 ax0 = {bia[0][0], bia[0][1], bia[0][2], bia[0][3]};
    f32x4 ax1 = {bia[1][0], bia[1][1], bia[1][2], bia[1][3]};
    f32x4 ax2 = {bia[2][0], bia[2][1], bia[2][2], bia[2][3]};
    f32x4 ax3 = {bia[3][0], bia[3][1], bia[3][2], bia[3][3]};
#pragma unroll
    for (int kk = 0; kk < 16; ++kk) {
      bf16x8 xv;
      if constexpr (FAST) {
        xv = __builtin_bit_cast(bf16x8, xpack[(size_t)t * 4096 + wv * 1024 + kk * 64 + lane]);
      } else {
        const float* xr = x + ((size_t)b * SEQ_LEN + t) * 512 + (kk << 5) + (hi2 << 3);
        f32x4 f0 = *(const f32x4*)(xr);
        f32x4 f1 = *(const f32x4*)(xr + 4);
        u32x4 v;
        v[0] = f2bf(f0[0]) | ((uint32)f2bf(f0[1]) << 16);
        v[1] = f2bf(f0[2]) | ((uint32)f2bf(f0[3]) << 16);
        v[2] = f2bf(f1[0]) | ((uint32)f2bf(f1[1]) << 16);
        v[3] = f2bf(f1[2]) | ((uint32)f2bf(f1[3]) << 16);
        xv = __builtin_bit_cast(bf16x8, v);
      }
      ax0 = __builtin_amdgcn_mfma_f32_16x16x32_bf16(
              __builtin_bit_cast(bf16x8, lA[(kk * 4 + 0) * 64 + lane]), xv, ax0, 0, 0, 0);
      ax1 = __builtin_amdgcn_mfma_f32_16x16x32_bf16(
              __builtin_bit_cast(bf16x8, lA[(kk * 4 + 1) * 64 + lane]), xv, ax1, 0, 0, 0);
      ax2 = __builtin_amdgcn_mfma_f32_16x16x32_bf16(
              __builtin_bit_cast(bf16x8, lA[(kk * 4 + 2) * 64 + lane]), xv, ax2, 0, 0, 0);
      ax3 = __builtin_amdgcn_mfma_f32_16x16x32_bf16(
              __builtin_bit_cast(bf16x8, lA[(kk * 4 + 3) * 64 + lane]), xv, ax3, 0, 0, 0);
    }

    if (t > 0) {
      if constexpr (FAST) {
        // ---- poll the 32 same-wave-index producer flags (dense 128B) ----
        const uint32* fa = flags + wv * 32 + (lane & 31);
        const uint32 tt = (uint32)t;
        while (true) {
          uint32 v;
          asm volatile("global_load_dword %0, %1, off sc0 sc1\n\ts_waitcnt vmcnt(0)"
                       : "=v"(v) : "v"(fa) : "memory");
          if (__all(v >= tt)) break;
        }
        __builtin_amdgcn_sched_barrier(0);
      }
      // ---- bulk h load: wave-contiguous 16KB, 1KB dense per instruction ----
      const u32x4* hr = (const u32x4*)(hbuf + (size_t)(t & 1) * 32768) + wv * 1024 + lane;
      u32x4 hreg[16];
      if constexpr (FAST) {
#pragma unroll
        for (int kk = 0; kk < 16; ++kk)
          asm volatile("global_load_dwordx4 %0, %1, off sc0 sc1"
                       : "=v"(hreg[kk]) : "v"(hr + kk * 64) : "memory");
        asm volatile("s_waitcnt vmcnt(0)" ::: "memory");
        __builtin_amdgcn_sched_barrier(0);
      } else {
#pragma unroll
        for (int kk = 0; kk < 16; ++kk) hreg[kk] = hr[kk * 64];
      }
#pragma unroll
      for (int kk = 0; kk < 16; ++kk) {
        bf16x8 hv = __builtin_bit_cast(bf16x8, hreg[kk]);
        ax0 = __builtin_amdgcn_mfma_f32_16x16x32_bf16(
                __builtin_bit_cast(bf16x8, lA[((16 + kk) * 4 + 0) * 64 + lane]), hv, ax0, 0, 0, 0);
        ax1 = __builtin_amdgcn_mfma_f32_16x16x32_bf16(
                __builtin_bit_cast(bf16x8, lA[((16 + kk) * 4 + 1) * 64 + lane]), hv, ax1, 0, 0, 0);
        ax2 = __builtin_amdgcn_mfma_f32_16x16x32_bf16(
                __builtin_bit_cast(bf16x8, lA[((16 + kk) * 4 + 2) * 64 + lane]), hv, ax2, 0, 0, 0);
        ax3 = __builtin_amdgcn_mfma_f32_16x16x32_bf16(
                __builtin_bit_cast(bf16x8, lA[((16 + kk) * 4 + 3) * 64 + lane]), hv, ax3, 0, 0, 0);
      }
    }

    // ---- cell update (4 cells per lane) ----
    f32x4 axv[4] = {ax0, ax1, ax2, ax3};
#pragma unroll
    for (int tau = 0; tau < 4; ++tau) {
      float gi = axv[tau][0], gf = axv[tau][1], gg = axv[tau][2], go = axv[tau][3];
      float it = sigm(gi), ft = sigm(gf), ot = sigm(go), gt = tanh_fast(gg);
      c[tau] = ft * c[tau] + it * gt;
      hn[tau] = ot * tanh_fast(c[tau]);
    }

    if (t < SEQ_LEN - 1) {
      ushort_t* hw = hbuf + (size_t)((t + 1) & 1) * 32768;
      if constexpr (FAST) {
#pragma unroll
        for (int tau = 0; tau < 4; ++tau) {
          uint32 v = f2bf(hn[tau]);
          asm volatile("global_store_short %0, %1, off sc0 sc1"
                       :: "v"(hw + uoff[tau]), "v"(v) : "memory");
        }
        asm volatile("s_waitcnt vmcnt(0)" ::: "memory");
        __builtin_amdgcn_sched_barrier(0);
        if (lane == 0) {                       // per-wave monotone flag
          uint32* fp = flags + wv * 32 + wg;
          uint32 val = (uint32)(t + 1);
          asm volatile("global_store_dword %0, %1, off sc0 sc1"
                       :: "v"(fp), "v"(val) : "memory");
        }
      } else {
#pragma unroll
        for (int tau = 0; tau < 4; ++tau) hw[uoff[tau]] = f2bf(hn[tau]);
        __threadfence();
        cg::this_grid().sync();
        __threadfence();
      }
    } else {
      if constexpr (!FAST) {
        __threadfence();
        cg::this_grid().sync();   // d_out aliases hbuf in slow path
      }
    }
  }

#pragma unroll
  for (int tau = 0; tau < 4; ++tau) {
    out[(size_t)b * 512 + kh[tau]] = hn[tau];
    out[32768 + (size_t)b * 512 + kh[tau]] = c[tau];
  }
}

extern "C" void kernel_launch(void* const* d_in, const int* in_sizes, int n_in,
                              void* d_out, int out_size, void* d_ws, size_t ws_size,
                              hipStream_t stream) {
  const float* x    = (const float*)d_in[0];
  const float* Wi   = (const float*)d_in[1];
  const float* Wh   = (const float*)d_in[2];
  const float* bias = (const float*)d_in[3];
  float* out = (float*)d_out;

  bool fast = (d_ws != nullptr) && (ws_size >= WS_NEED);

  if (fast) {
    const u32x4* xpack = (const u32x4*)d_ws;
    const u32x4* wpack = (const u32x4*)((char*)d_ws + XPACK_BYTES);
    ushort_t* hbuf = (ushort_t*)((char*)d_ws + HB_OFF);
    uint32* flags  = (uint32*)((char*)d_ws + FLG_OFF);

    zero_mem_kernel<<<1, 32, 0, stream>>>((u32x4*)((char*)d_ws + FLG_OFF)); // 512B flags
    pack_x_kernel<<<16384, 256, 0, stream>>>(x, (u32x4*)d_ws);
    pack_w_kernel<<<8192, 256, 0, stream>>>(Wi, Wh, (ushort_t*)((char*)d_ws + XPACK_BYTES));

    lstm_coop<true><<<dim3(NWG), dim3(NTHR), 0, stream>>>(
        x, Wi, Wh, bias, xpack, wpack, hbuf, flags, out);
  } else {
    ushort_t* hbuf = (ushort_t*)d_out;   // two 64KB slots inside 256KB d_out
    uint32* flags = (uint32*)d_out;      // unused on slow path
    const u32x4* xpack = (const u32x4*)x;
    const u32x4* wpack = (const u32x4*)Wi;

    void* args[] = {(void*)&x, (void*)&Wi, (void*)&Wh, (void*)&bias,
                    (void*)&xpack, (void*)&wpack, (void*)&hbuf, (void*)&flags, (void*)&out};
    void (*kfn)(const float*, const float*, const float*, const float*,
                const u32x4*, const u32x4*, ushort_t*, uint32*, float*) = lstm_coop<false>;
    hipLaunchCooperativeKernel(reinterpret_cast<void*>(kfn), dim3(NWG), dim3(NTHR),
                               args, 0, stream);
  }
}